// Round 17
// baseline (232.719 us; speedup 1.0000x reference)
//
#include <hip/hip_runtime.h>
#include <math.h>

#define NUM_LEVELS 16
#define LOG2_T 21
#define TABLE_SIZE (1u << LOG2_T)
#define HASH_MASK (TABLE_SIZE - 1u)
#define N_POINTS 262144
#define GRID_P1 512            // 64 slices x 8 xcd-slots; 2 blocks/CU, zero tail
#define PTS_PER_BLOCK 4096     // 16 pts/thread x 256 threads
#define PX 73856093u
#define PY 19349663u
#define PZ 83492791u

struct Args { float r[NUM_LEVELS]; int l2nc[NUM_LEVELS]; };

// two-level paste so trailing digit doesn't fuse with ".x" into one pp-token
#define CAT3_(a, b, c) a##b##c
#define TREG(SET, i) CAT3_(t, SET, i)

#define CORNER(SET, i)                                                        \
    {                                                                         \
        const uint32_t h = (((i) & 4) ? X1 : X0) ^ (((i) & 2) ? Y1 : Y0)      \
                         ^ (((i) & 1) ? Z1 : Z0);                             \
        const uint32_t idx = h & HASH_MASK;                                   \
        const bool m = (idx >> shift) == (uint32_t)c;                         \
        const uint32_t off = m ? (idx << 3) : dummy_off;                      \
        wc##SET[i] = m ? (((((i) & 4) ? qx : axq) * (((i) & 2) ? qy : ayq))   \
                          * (((i) & 1) ? qz : azq))                           \
                       : 0.0f;                                                \
        asm volatile("global_load_dwordx2 %0, %1, %2"                         \
                     : "=v"(TREG(SET, i)) : "v"(off), "s"(tab));              \
    }

#define ISSUE(SET, p)                                                         \
    {                                                                         \
        const float sx = nxx[p] * r, sy = nyy[p] * r, sz = nzz[p] * r;        \
        const float fx = floorf(sx), fy = floorf(sy), fz = floorf(sz);        \
        const float qx = sx - fx, qy = sy - fy, qz = sz - fz;                 \
        const float axq = 1.0f - qx, ayq = 1.0f - qy, azq = 1.0f - qz;        \
        const uint32_t X0 = (uint32_t)(int)fx * PX;                           \
        const uint32_t Y0 = (uint32_t)(int)fy * PY;                           \
        const uint32_t Z0 = (uint32_t)(int)fz * PZ;                           \
        const uint32_t X1 = X0 + PX, Y1 = Y0 + PY, Z1 = Z0 + PZ;              \
        CORNER(SET, 0) CORNER(SET, 1) CORNER(SET, 2) CORNER(SET, 3)           \
        CORNER(SET, 4) CORNER(SET, 5) CORNER(SET, 6) CORNER(SET, 7)           \
    }

#define WAIT(SET, CNT)                                                        \
    asm volatile("s_waitcnt vmcnt(" #CNT ")"                                  \
                 : "+v"(TREG(SET, 0)), "+v"(TREG(SET, 1)),                    \
                   "+v"(TREG(SET, 2)), "+v"(TREG(SET, 3)),                    \
                   "+v"(TREG(SET, 4)), "+v"(TREG(SET, 5)),                    \
                   "+v"(TREG(SET, 6)), "+v"(TREG(SET, 7)));

#define FMA2(SET, p, i)                                                       \
    a0[p] = fmaf(wc##SET[i], TREG(SET, i).x, a0[p]);                          \
    a1[p] = fmaf(wc##SET[i], TREG(SET, i).y, a1[p]);

#define FMA8(SET, p)                                                          \
    FMA2(SET, p, 0) FMA2(SET, p, 1) FMA2(SET, p, 2) FMA2(SET, p, 3)           \
    FMA2(SET, p, 4) FMA2(SET, p, 5) FMA2(SET, p, 6) FMA2(SET, p, 7)

// ---- phase 1: zero-tail cohort, XCD-pinned levels, L2 chunks, 2-deep pipe --
__global__ __launch_bounds__(256) void hash_embed_phase1_v17(
    const float* __restrict__ x,
    const float* __restrict__ tables,
    float2* __restrict__ wsbuf,       // [NUM_LEVELS][N_POINTS]
    Args args)
{
    const int bid = blockIdx.x;
    const int slot = bid & 7;          // dispatch-order XCD heuristic (perf-only)
    const int slice = bid >> 3;        // 0..63
    const int base = slice * PTS_PER_BLOCK + threadIdx.x;

    // persistent across BOTH levels: clamped normalized coords (x read once)
    float nxx[16], nyy[16], nzz[16];
    #pragma unroll
    for (int p = 0; p < 16; ++p) {
        const int n = base + p * 256;
        const float px = x[n * 3 + 0];
        const float py = x[n * 3 + 1];
        const float pz = x[n * 3 + 2];
        nxx[p] = fminf(fmaxf((px + 2.0f) * 0.25f, 0.0f), 1.0f);
        nyy[p] = fminf(fmaxf((py + 2.0f) * 0.25f, 0.0f), 1.0f);
        nzz[p] = fminf(fmaxf((pz + 2.0f) * 0.25f, 0.0f), 1.0f);
    }

    #pragma unroll 1
    for (int li = 0; li < 2; ++li) {
        const int lv = (li == 0) ? slot : 15 - slot;
        const float r = args.r[lv];
        const int l2nc = args.l2nc[lv];
        const int shift = LOG2_T - l2nc;
        const int nc = 1 << l2nc;
        const float* __restrict__ tab =
            tables + (size_t)lv * ((size_t)TABLE_SIZE * 2);

        float a0[16], a1[16];
        #pragma unroll
        for (int p = 0; p < 16; ++p) { a0[p] = 0.0f; a1[p] = 0.0f; }

        #pragma unroll 1
        for (int c = 0; c < nc; ++c) {
            const uint32_t dummy_off = ((uint32_t)c << shift) << 3;  // in-chunk line
            float2 tA0, tA1, tA2, tA3, tA4, tA5, tA6, tA7;
            float2 tB0, tB1, tB2, tB3, tB4, tB5, tB6, tB7;
            float wcA[8], wcB[8];

            // 2-deep software pipeline over 16 points: 8-16 loads in flight
            ISSUE(A, 0)
            ISSUE(B, 1)  WAIT(A, 8) FMA8(A, 0)
            ISSUE(A, 2)  WAIT(B, 8) FMA8(B, 1)
            ISSUE(B, 3)  WAIT(A, 8) FMA8(A, 2)
            ISSUE(A, 4)  WAIT(B, 8) FMA8(B, 3)
            ISSUE(B, 5)  WAIT(A, 8) FMA8(A, 4)
            ISSUE(A, 6)  WAIT(B, 8) FMA8(B, 5)
            ISSUE(B, 7)  WAIT(A, 8) FMA8(A, 6)
            ISSUE(A, 8)  WAIT(B, 8) FMA8(B, 7)
            ISSUE(B, 9)  WAIT(A, 8) FMA8(A, 8)
            ISSUE(A, 10) WAIT(B, 8) FMA8(B, 9)
            ISSUE(B, 11) WAIT(A, 8) FMA8(A, 10)
            ISSUE(A, 12) WAIT(B, 8) FMA8(B, 11)
            ISSUE(B, 13) WAIT(A, 8) FMA8(A, 12)
            ISSUE(A, 14) WAIT(B, 8) FMA8(B, 13)
            ISSUE(B, 15) WAIT(A, 8) FMA8(A, 14)
                         WAIT(B, 0) FMA8(B, 15)
        }

        #pragma unroll
        for (int p = 0; p < 16; ++p) {
            wsbuf[(size_t)lv * N_POINTS + base + p * 256] = make_float2(a0[p], a1[p]);
        }
    }
}

// ---- phase 2: transpose ws[l][n] -> out[n][l] ------------------------------
__global__ __launch_bounds__(256) void hash_embed_phase2(
    const float2* __restrict__ ws,
    float2* __restrict__ out)
{
    __shared__ float2 tile[64][NUM_LEVELS + 1];
    const int n0 = blockIdx.x * 64;
    const int t = threadIdx.x;
    #pragma unroll
    for (int k = 0; k < 4; ++k) {
        const int e = k * 256 + t;
        const int l = e >> 6;
        const int j = e & 63;
        tile[j][l] = ws[(size_t)l * N_POINTS + n0 + j];
    }
    __syncthreads();
    #pragma unroll
    for (int k = 0; k < 4; ++k) {
        const int e = k * 256 + t;
        const int nl = e >> 4;
        const int l = e & 15;
        out[(size_t)(n0 + nl) * NUM_LEVELS + l] = tile[nl][l];
    }
}

// ---- fallback (R1-proven): interleaved levels, direct out ------------------
__global__ __launch_bounds__(256) void hash_embed_direct(
    const float* __restrict__ x,
    const float* __restrict__ tables,
    float* __restrict__ out,
    Args args)
{
    const int t = blockIdx.x * blockDim.x + threadIdx.x;
    const int n = t >> 4;
    const int l = t & 15;
    if (n >= N_POINTS) return;

    const float px = x[n * 3 + 0];
    const float py = x[n * 3 + 1];
    const float pz = x[n * 3 + 2];
    const float nx = fminf(fmaxf((px + 2.0f) * 0.25f, 0.0f), 1.0f);
    const float ny = fminf(fmaxf((py + 2.0f) * 0.25f, 0.0f), 1.0f);
    const float nz = fminf(fmaxf((pz + 2.0f) * 0.25f, 0.0f), 1.0f);

    const float r = args.r[l];
    const float sx = nx * r, sy = ny * r, sz = nz * r;
    const float fx = floorf(sx), fy = floorf(sy), fz = floorf(sz);
    const float wxv = sx - fx, wyv = sy - fy, wzv = sz - fz;

    const uint32_t hx0 = (uint32_t)(int)fx * PX;
    const uint32_t hy0 = (uint32_t)(int)fy * PY;
    const uint32_t hz0 = (uint32_t)(int)fz * PZ;
    const uint32_t hx1 = hx0 + PX, hy1 = hy0 + PY, hz1 = hz0 + PZ;

    const float ax = 1.0f - wxv, ay = 1.0f - wyv, az = 1.0f - wzv;
    const float* __restrict__ tab = tables + (size_t)l * ((size_t)TABLE_SIZE * 2);

    float f0 = 0.0f, f1 = 0.0f;
    #pragma unroll
    for (int c = 0; c < 8; ++c) {
        const uint32_t hh = ((c & 4) ? hx1 : hx0) ^ ((c & 2) ? hy1 : hy0)
                          ^ ((c & 1) ? hz1 : hz0);
        const uint32_t idx = hh & HASH_MASK;
        const float2 emb = *reinterpret_cast<const float2*>(tab + (size_t)idx * 2);
        const float w = (((c & 4) ? wxv : ax) * ((c & 2) ? wyv : ay)) * ((c & 1) ? wzv : az);
        f0 = fmaf(w, emb.x, f0);
        f1 = fmaf(w, emb.y, f1);
    }
    float2* o = reinterpret_cast<float2*>(out + (size_t)n * (NUM_LEVELS * 2) + l * 2);
    *o = make_float2(f0, f1);
}

extern "C" void kernel_launch(void* const* d_in, const int* in_sizes, int n_in,
                              void* d_out, int out_size, void* d_ws, size_t ws_size,
                              hipStream_t stream) {
    const float* x      = (const float*)d_in[0];
    const float* tables = (const float*)d_in[1];
    float* out          = (float*)d_out;

    Args args;
    const double b = exp((log(2048.0) - log(16.0)) / 15.0);
    for (int i = 0; i < NUM_LEVELS; ++i) {
        const double ri = floor(16.0 * pow(b, (double)i));
        args.r[i] = (float)ri;
        // accessed-footprint model: E distinct corners hash-spread over 2^21
        // slots, 8 entries per 64B line
        double E = (ri + 1.0) * (ri + 1.0) * (ri + 1.0);
        if (E > 1.8e6) E = 1.8e6;
        const double lines = 262144.0 * (1.0 - exp(-8.0 * E / 2097152.0));
        const double bytes = lines * 64.0;
        // chunk so each chunk's footprint fits L2 (~3.7 MB target), max nc=8
        int l2 = 0;
        while (l2 < 3 && bytes / (double)(1 << l2) > 3.7e6) ++l2;
        args.l2nc[i] = l2;
    }

    const size_t ws_needed = (size_t)NUM_LEVELS * N_POINTS * sizeof(float2); // 32 MB
    if (ws_size >= ws_needed) {
        float2* wsbuf = (float2*)d_ws;
        hipLaunchKernelGGL(hash_embed_phase1_v17, dim3(GRID_P1), dim3(256),
                           0, stream, x, tables, wsbuf, args);
        hipLaunchKernelGGL(hash_embed_phase2, dim3(N_POINTS / 64), dim3(256),
                           0, stream, wsbuf, (float2*)out);
    } else {
        const int total = N_POINTS * NUM_LEVELS;
        hipLaunchKernelGGL(hash_embed_direct, dim3((total + 255) / 256), dim3(256),
                           0, stream, x, tables, out, args);
    }
}

// Round 18
// 224.051 us; speedup vs baseline: 1.0387x; 1.0387x over previous
//
#include <hip/hip_runtime.h>
#include <math.h>

#define NUM_LEVELS 16
#define LOG2_T 21
#define TABLE_SIZE (1u << LOG2_T)
#define HASH_MASK (TABLE_SIZE - 1u)
#define N_POINTS 262144
#define GRID_P1 1024           // 128 slices x 8 xcd-slots
#define PTS_PER_BLOCK 2048     // 8 pts/thread x 256 threads
#define PX 73856093u
#define PY 19349663u
#define PZ 83492791u

struct Args { float r[NUM_LEVELS]; int l2nc[NUM_LEVELS]; };

// two-level paste so trailing digit doesn't fuse with ".x" into one pp-token
#define CAT3_(a, b, c) a##b##c
#define TREG(SET, i) CAT3_(t, SET, i)

// Issue 8 corner loads for point p into register set SET; weights in wc##SET.
// Recomputes floor/frac/hash from persistent nx/ny/nz (keeps live state small).
#define CORNER(SET, i)                                                        \
    {                                                                         \
        const uint32_t h = (((i) & 4) ? X1 : X0) ^ (((i) & 2) ? Y1 : Y0)      \
                         ^ (((i) & 1) ? Z1 : Z0);                             \
        const uint32_t idx = h & HASH_MASK;                                   \
        const bool m = (idx >> shift) == (uint32_t)c;                         \
        const uint32_t off = m ? (idx << 3) : dummy_off;                      \
        wc##SET[i] = m ? (((((i) & 4) ? qx : axq) * (((i) & 2) ? qy : ayq))   \
                          * (((i) & 1) ? qz : azq))                           \
                       : 0.0f;                                                \
        asm volatile("global_load_dwordx2 %0, %1, %2"                         \
                     : "=v"(TREG(SET, i)) : "v"(off), "s"(tab));              \
    }

#define ISSUE(SET, p)                                                         \
    {                                                                         \
        const float sx = nxx[p] * r, sy = nyy[p] * r, sz = nzz[p] * r;        \
        const float fx = floorf(sx), fy = floorf(sy), fz = floorf(sz);        \
        const float qx = sx - fx, qy = sy - fy, qz = sz - fz;                 \
        const float axq = 1.0f - qx, ayq = 1.0f - qy, azq = 1.0f - qz;        \
        const uint32_t X0 = (uint32_t)(int)fx * PX;                           \
        const uint32_t Y0 = (uint32_t)(int)fy * PY;                           \
        const uint32_t Z0 = (uint32_t)(int)fz * PZ;                           \
        const uint32_t X1 = X0 + PX, Y1 = Y0 + PY, Z1 = Z0 + PZ;              \
        CORNER(SET, 0) CORNER(SET, 1) CORNER(SET, 2) CORNER(SET, 3)           \
        CORNER(SET, 4) CORNER(SET, 5) CORNER(SET, 6) CORNER(SET, 7)           \
    }

#define WAIT(SET, CNT)                                                        \
    asm volatile("s_waitcnt vmcnt(" #CNT ")"                                  \
                 : "+v"(TREG(SET, 0)), "+v"(TREG(SET, 1)),                    \
                   "+v"(TREG(SET, 2)), "+v"(TREG(SET, 3)),                    \
                   "+v"(TREG(SET, 4)), "+v"(TREG(SET, 5)),                    \
                   "+v"(TREG(SET, 6)), "+v"(TREG(SET, 7)));

#define FMA2(SET, p, i)                                                       \
    a0[p] = fmaf(wc##SET[i], TREG(SET, i).x, a0[p]);                          \
    a1[p] = fmaf(wc##SET[i], TREG(SET, i).y, a1[p]);

#define FMA8(SET, p)                                                          \
    FMA2(SET, p, 0) FMA2(SET, p, 1) FMA2(SET, p, 2) FMA2(SET, p, 3)           \
    FMA2(SET, p, 4) FMA2(SET, p, 5) FMA2(SET, p, 6) FMA2(SET, p, 7)

// ---- phase 1: co-resident cohort, XCD-pinned levels, L2 chunks, 2-deep pipe
__global__ __launch_bounds__(256) void hash_embed_phase1_v18(
    const float* __restrict__ x,
    const float* __restrict__ tables,
    float2* __restrict__ wsbuf,       // [NUM_LEVELS][N_POINTS]
    Args args)
{
    const int bid = blockIdx.x;
    const int slot = bid & 7;          // dispatch-order XCD heuristic (perf-only)
    const int slice = bid >> 3;        // 0..127
    const int base = slice * PTS_PER_BLOCK + threadIdx.x;

    // persistent across BOTH levels: clamped normalized coords (x read once)
    float nxx[8], nyy[8], nzz[8];
    #pragma unroll
    for (int p = 0; p < 8; ++p) {
        const int n = base + p * 256;
        const float px = x[n * 3 + 0];
        const float py = x[n * 3 + 1];
        const float pz = x[n * 3 + 2];
        nxx[p] = fminf(fmaxf((px + 2.0f) * 0.25f, 0.0f), 1.0f);
        nyy[p] = fminf(fmaxf((py + 2.0f) * 0.25f, 0.0f), 1.0f);
        nzz[p] = fminf(fmaxf((pz + 2.0f) * 0.25f, 0.0f), 1.0f);
    }

    #pragma unroll 1
    for (int li = 0; li < 2; ++li) {
        const int lv = (li == 0) ? slot : 15 - slot;
        const float r = args.r[lv];
        const int l2nc = args.l2nc[lv];
        const int shift = LOG2_T - l2nc;
        const int nc = 1 << l2nc;
        const float* __restrict__ tab =
            tables + (size_t)lv * ((size_t)TABLE_SIZE * 2);

        float a0[8], a1[8];
        #pragma unroll
        for (int p = 0; p < 8; ++p) { a0[p] = 0.0f; a1[p] = 0.0f; }

        #pragma unroll 1
        for (int c = 0; c < nc; ++c) {
            const uint32_t dummy_off = ((uint32_t)c << shift) << 3;  // in-chunk line
            float2 tA0, tA1, tA2, tA3, tA4, tA5, tA6, tA7;
            float2 tB0, tB1, tB2, tB3, tB4, tB5, tB6, tB7;
            float wcA[8], wcB[8];

            // 2-deep software pipeline: 8-16 loads in flight per wave
            ISSUE(A, 0)
            ISSUE(B, 1) WAIT(A, 8) FMA8(A, 0)
            ISSUE(A, 2) WAIT(B, 8) FMA8(B, 1)
            ISSUE(B, 3) WAIT(A, 8) FMA8(A, 2)
            ISSUE(A, 4) WAIT(B, 8) FMA8(B, 3)
            ISSUE(B, 5) WAIT(A, 8) FMA8(A, 4)
            ISSUE(A, 6) WAIT(B, 8) FMA8(B, 5)
            ISSUE(B, 7) WAIT(A, 8) FMA8(A, 6)
                        WAIT(B, 0) FMA8(B, 7)
        }

        #pragma unroll
        for (int p = 0; p < 8; ++p) {
            wsbuf[(size_t)lv * N_POINTS + base + p * 256] = make_float2(a0[p], a1[p]);
        }
    }
}

// ---- phase 2: transpose ws[l][n] -> out[n][l] ------------------------------
__global__ __launch_bounds__(256) void hash_embed_phase2(
    const float2* __restrict__ ws,
    float2* __restrict__ out)
{
    __shared__ float2 tile[64][NUM_LEVELS + 1];
    const int n0 = blockIdx.x * 64;
    const int t = threadIdx.x;
    #pragma unroll
    for (int k = 0; k < 4; ++k) {
        const int e = k * 256 + t;
        const int l = e >> 6;
        const int j = e & 63;
        tile[j][l] = ws[(size_t)l * N_POINTS + n0 + j];
    }
    __syncthreads();
    #pragma unroll
    for (int k = 0; k < 4; ++k) {
        const int e = k * 256 + t;
        const int nl = e >> 4;
        const int l = e & 15;
        out[(size_t)(n0 + nl) * NUM_LEVELS + l] = tile[nl][l];
    }
}

// ---- fallback (R1-proven): interleaved levels, direct out ------------------
__global__ __launch_bounds__(256) void hash_embed_direct(
    const float* __restrict__ x,
    const float* __restrict__ tables,
    float* __restrict__ out,
    Args args)
{
    const int t = blockIdx.x * blockDim.x + threadIdx.x;
    const int n = t >> 4;
    const int l = t & 15;
    if (n >= N_POINTS) return;

    const float px = x[n * 3 + 0];
    const float py = x[n * 3 + 1];
    const float pz = x[n * 3 + 2];
    const float nx = fminf(fmaxf((px + 2.0f) * 0.25f, 0.0f), 1.0f);
    const float ny = fminf(fmaxf((py + 2.0f) * 0.25f, 0.0f), 1.0f);
    const float nz = fminf(fmaxf((pz + 2.0f) * 0.25f, 0.0f), 1.0f);

    const float r = args.r[l];
    const float sx = nx * r, sy = ny * r, sz = nz * r;
    const float fx = floorf(sx), fy = floorf(sy), fz = floorf(sz);
    const float wxv = sx - fx, wyv = sy - fy, wzv = sz - fz;

    const uint32_t hx0 = (uint32_t)(int)fx * PX;
    const uint32_t hy0 = (uint32_t)(int)fy * PY;
    const uint32_t hz0 = (uint32_t)(int)fz * PZ;
    const uint32_t hx1 = hx0 + PX, hy1 = hy0 + PY, hz1 = hz0 + PZ;

    const float ax = 1.0f - wxv, ay = 1.0f - wyv, az = 1.0f - wzv;
    const float* __restrict__ tab = tables + (size_t)l * ((size_t)TABLE_SIZE * 2);

    float f0 = 0.0f, f1 = 0.0f;
    #pragma unroll
    for (int c = 0; c < 8; ++c) {
        const uint32_t hh = ((c & 4) ? hx1 : hx0) ^ ((c & 2) ? hy1 : hy0)
                          ^ ((c & 1) ? hz1 : hz0);
        const uint32_t idx = hh & HASH_MASK;
        const float2 emb = *reinterpret_cast<const float2*>(tab + (size_t)idx * 2);
        const float w = (((c & 4) ? wxv : ax) * ((c & 2) ? wyv : ay)) * ((c & 1) ? wzv : az);
        f0 = fmaf(w, emb.x, f0);
        f1 = fmaf(w, emb.y, f1);
    }
    float2* o = reinterpret_cast<float2*>(out + (size_t)n * (NUM_LEVELS * 2) + l * 2);
    *o = make_float2(f0, f1);
}

extern "C" void kernel_launch(void* const* d_in, const int* in_sizes, int n_in,
                              void* d_out, int out_size, void* d_ws, size_t ws_size,
                              hipStream_t stream) {
    const float* x      = (const float*)d_in[0];
    const float* tables = (const float*)d_in[1];
    float* out          = (float*)d_out;

    Args args;
    const double b = exp((log(2048.0) - log(16.0)) / 15.0);
    for (int i = 0; i < NUM_LEVELS; ++i) {
        const double ri = floor(16.0 * pow(b, (double)i));
        args.r[i] = (float)ri;
        // accessed-footprint model: E distinct corners hash-spread over 2^21
        // slots, 8 entries per 64B line
        double E = (ri + 1.0) * (ri + 1.0) * (ri + 1.0);
        if (E > 1.8e6) E = 1.8e6;
        const double lines = 262144.0 * (1.0 - exp(-8.0 * E / 2097152.0));
        const double bytes = lines * 64.0;
        // chunk so each chunk ~fits L2 (4.5 MB target), cap nc=4:
        // fewer passes = fewer gather lane-slots (the measured wall, R17)
        int l2 = 0;
        while (l2 < 2 && bytes / (double)(1 << l2) > 4.5e6) ++l2;
        args.l2nc[i] = l2;
    }

    const size_t ws_needed = (size_t)NUM_LEVELS * N_POINTS * sizeof(float2); // 32 MB
    if (ws_size >= ws_needed) {
        float2* wsbuf = (float2*)d_ws;
        hipLaunchKernelGGL(hash_embed_phase1_v18, dim3(GRID_P1), dim3(256),
                           0, stream, x, tables, wsbuf, args);
        hipLaunchKernelGGL(hash_embed_phase2, dim3(N_POINTS / 64), dim3(256),
                           0, stream, wsbuf, (float2*)out);
    } else {
        const int total = N_POINTS * NUM_LEVELS;
        hipLaunchKernelGGL(hash_embed_direct, dim3((total + 255) / 256), dim3(256),
                           0, stream, x, tables, out, args);
    }
}